// Round 6
// baseline (5392.867 us; speedup 1.0000x reference)
//
#include <hip/hip_runtime.h>
#include <cstdint>
#include <cstddef>

#define B_ 64
#define S_ 512
#define I_ 256
#define H_ 512
#define E_ 512

typedef __attribute__((ext_vector_type(8))) short bf16x8;
typedef __attribute__((ext_vector_type(4))) float f32x4;

__device__ __forceinline__ unsigned short f2b(float x) {
    uint32_t u = __builtin_bit_cast(uint32_t, x);
    uint32_t r = u + 0x7fffu + ((u >> 16) & 1u);
    return (unsigned short)(r >> 16);
}

// Compiler-only ordering for type-punned LDS repack (round-3 lesson:
// uint64_t does not TBAA-alias unsigned short; HW keeps DS ops in order).
__device__ __forceinline__ void lds_repack_fence() {
    __atomic_signal_fence(__ATOMIC_SEQ_CST);
    __builtin_amdgcn_wave_barrier();
}

// Compiler-only: keep relaxed data loads from being hoisted above the poll.
__device__ __forceinline__ void poll_fence() {
    __atomic_signal_fence(__ATOMIC_SEQ_CST);
}

__device__ __forceinline__ int ctr_ld(const int* p) {
    return __hip_atomic_load(p, __ATOMIC_RELAXED, __HIP_MEMORY_SCOPE_AGENT);
}
__device__ __forceinline__ uint64_t st_ld(const uint64_t* p) {
    return __hip_atomic_load(p, __ATOMIC_RELAXED, __HIP_MEMORY_SCOPE_AGENT);
}
__device__ __forceinline__ void st_st(uint64_t* p, uint64_t v) {
    __hip_atomic_store(p, v, __ATOMIC_RELAXED, __HIP_MEMORY_SCOPE_AGENT);
}

// ---- convert the three 512x512 recurrent matrices to bf16 (row-major) ----
__global__ __launch_bounds__(256) void conv_bf16(const float* __restrict__ whh,
                                                 const float* __restrict__ wya,
                                                 const float* __restrict__ waa,
                                                 unsigned short* __restrict__ owhh,
                                                 unsigned short* __restrict__ owya,
                                                 unsigned short* __restrict__ owaa) {
    int i = blockIdx.x * 256 + threadIdx.x;
    owhh[i] = f2b(whh[i]);
    owya[i] = f2b(wya[i]);
    owaa[i] = f2b(waa[i]);
}

__global__ __launch_bounds__(256) void init_state(uint32_t* __restrict__ p, int n) {
    int i = blockIdx.x * 256 + threadIdx.x;
    if (i < n) p[i] = 0u;
}

// ---------------- xw GEMM (fp32, unchanged — verified) ----------------
__global__ __launch_bounds__(256) void xw_gemm(const float* __restrict__ x,
                                               const float* __restrict__ W_ih,
                                               const float* __restrict__ b_ih,
                                               const float* __restrict__ b_hh,
                                               float* __restrict__ xw) {
    __shared__ float As[16][65];
    __shared__ float Bs[16][65];
    const int tid = threadIdx.x;
    const int m0 = blockIdx.y * 64;
    const int n0 = blockIdx.x * 64;

    const int lr = tid >> 2;
    const int lk = (tid & 3) * 4;

    const int m = m0 + lr;
    const float* xrow = x + ((size_t)(m & 63) * S_ + (m >> 6)) * I_;
    const float* brow = W_ih + (size_t)(n0 + lr) * I_;

    const int tm = (tid >> 4) * 4;
    const int tn = (tid & 15) * 4;

    float acc[4][4] = {{0.f}};

    for (int kt = 0; kt < I_; kt += 16) {
        float4 av = *(const float4*)(xrow + kt + lk);
        float4 bv = *(const float4*)(brow + kt + lk);
        As[lk + 0][lr] = av.x; As[lk + 1][lr] = av.y;
        As[lk + 2][lr] = av.z; As[lk + 3][lr] = av.w;
        Bs[lk + 0][lr] = bv.x; Bs[lk + 1][lr] = bv.y;
        Bs[lk + 2][lr] = bv.z; Bs[lk + 3][lr] = bv.w;
        __syncthreads();
#pragma unroll
        for (int k = 0; k < 16; ++k) {
            float a0 = As[k][tm + 0], a1 = As[k][tm + 1], a2 = As[k][tm + 2], a3 = As[k][tm + 3];
            float c0 = Bs[k][tn + 0], c1 = Bs[k][tn + 1], c2 = Bs[k][tn + 2], c3 = Bs[k][tn + 3];
            acc[0][0] += a0 * c0; acc[0][1] += a0 * c1; acc[0][2] += a0 * c2; acc[0][3] += a0 * c3;
            acc[1][0] += a1 * c0; acc[1][1] += a1 * c1; acc[1][2] += a1 * c2; acc[1][3] += a1 * c3;
            acc[2][0] += a2 * c0; acc[2][1] += a2 * c1; acc[2][2] += a2 * c2; acc[2][3] += a2 * c3;
            acc[3][0] += a3 * c0; acc[3][1] += a3 * c1; acc[3][2] += a3 * c2; acc[3][3] += a3 * c3;
        }
        __syncthreads();
    }

#pragma unroll
    for (int i = 0; i < 4; ++i) {
        int row = m0 + tm + i;
#pragma unroll
        for (int j = 0; j < 4; ++j) {
            int n = n0 + tn + j;
            xw[(size_t)row * H_ + n] = acc[i][j] + b_ih[n] + b_hh[n];
        }
    }
}

// ---------------- wave-autonomous MFMA scan ----------------
// 48 WGs x 256 threads, NO __syncthreads in the steady-state loop.
// blocks 0..15  : h-WGs. 4 per group g (g = bid>>2). Wave w owns 32 h-cols
//                 jw = (bid&3)*128 + w*32, with private LDS Whh B-frags.
//                 step t: h_t = tanh(xw_t + Whh h_{t-1}).
// blocks 16..47 : a-WGs. 8 per group (g = (bid-16)>>3). Wave w owns 16 a-cols
//                 jw = ((bid-16)&7)*64 + w*16, private Wya+Waa frags.
//                 step t: a_t = tanh(Wya h_t + Waa a_{t-1} + bias).
// Flags: hctr[g] += 1 per h-WAVE per step, SIGNALED BY LANE 0 ONLY (round-5
// bug: unguarded fetch_add ran on all 64 lanes -> counters advanced 64x too
// fast -> every poll passed early -> garbage). RELEASE add drains the whole
// wave's stores (s_waitcnt vmcnt(0) is wave-level) before the signal.
// h ring depth 8 (WAR guard: actr>=32*(t-8)); a ring depth 2 (poll
// actr>=32*(t-1) implies a_{t-2} fully consumed before overwrite).
__global__ __launch_bounds__(256) void scan_mfma(const float* __restrict__ xw,
                                                 const unsigned short* __restrict__ Whh_b,
                                                 const unsigned short* __restrict__ Wya_b,
                                                 const unsigned short* __restrict__ Waa_b,
                                                 const float* __restrict__ b_ya,
                                                 const float* __restrict__ b_aa,
                                                 unsigned short* __restrict__ hring,  // 8*64*512 bf16
                                                 unsigned short* __restrict__ aring,  // 2*64*512 bf16
                                                 int* __restrict__ ctr,               // hctr[g]@g*64, actr[g]@(4+g)*64
                                                 float* __restrict__ out) {
    const int bid  = blockIdx.x;
    const int tid  = threadIdx.x;
    const int wave = tid >> 6;
    const int lane = tid & 63;
    const int l15  = lane & 15;
    const int quad = lane >> 4;

    __shared__ unsigned short wlds[4 * 2 * 16 * 64 * 8];  // 128 KB, per-wave partition
    __shared__ unsigned short pk[4][512];                  // per-wave repack staging

    uint64_t* hr64 = (uint64_t*)hring;
    uint64_t* ar64 = (uint64_t*)aring;

    if (bid < 16) {
        // ---------------- h-side ----------------
        const int g   = bid >> 2;
        const int b0  = g * 16;
        const int jw  = (bid & 3) * 128 + wave * 32;
        int* hc = ctr + g * 64;
        int* ac = ctr + (4 + g) * 64;

        // stage private Whh B-frags: B[k][j] = Whh[j][k], 16B/lane/frag
#pragma unroll
        for (int idx = 0; idx < 32; ++idx) {
            int s = idx >> 4, kb = idx & 15;
            const unsigned short* src = Whh_b + (size_t)(jw + s * 16 + l15) * H_ + kb * 32 + quad * 8;
            *(uint4*)&wlds[(((wave * 2 + s) * 16 + kb) * 64 + lane) * 8] = *(const uint4*)src;
        }
        lds_repack_fence();   // staging stores (uint4) vs loop reads (bf16x8): TBAA

        unsigned short* mypk = &pk[wave][0];
        const int prow = lane >> 2, pcg = lane & 3;

        for (int t = 1; t <= S_; ++t) {
            // xw prefetch: issued before polls, consumed after MFMA
            float xwv[2][4];
#pragma unroll
            for (int s = 0; s < 2; ++s)
#pragma unroll
                for (int r = 0; r < 4; ++r)
                    xwv[s][r] = xw[((size_t)(t - 1) * B_ + b0 + quad * 4 + r) * H_ + jw + s * 16 + l15];

            if (t > 8) while (ctr_ld(ac) < 32 * (t - 8)) {}   // h-ring WAR guard
            while (ctr_ld(hc) < 16 * (t - 1)) {}              // h_{t-1} ready
            poll_fence();

            const uint64_t* hsrc = hr64 + (size_t)((t - 1) & 7) * 8192 + (size_t)(b0 + l15) * 128 + quad * 2;
            union { uint64_t q[2]; bf16x8 v; } hf[16];
#pragma unroll
            for (int kb = 0; kb < 16; ++kb) {
                hf[kb].q[0] = st_ld(hsrc + kb * 8);
                hf[kb].q[1] = st_ld(hsrc + kb * 8 + 1);
            }
            f32x4 a0 = {0.f, 0.f, 0.f, 0.f}, a1 = {0.f, 0.f, 0.f, 0.f};
#pragma unroll
            for (int kb = 0; kb < 16; ++kb) {
                bf16x8 b0f = *(const bf16x8*)&wlds[(((wave * 2 + 0) * 16 + kb) * 64 + lane) * 8];
                bf16x8 b1f = *(const bf16x8*)&wlds[(((wave * 2 + 1) * 16 + kb) * 64 + lane) * 8];
                a0 = __builtin_amdgcn_mfma_f32_16x16x32_bf16(hf[kb].v, b0f, a0, 0, 0, 0);
                a1 = __builtin_amdgcn_mfma_f32_16x16x32_bf16(hf[kb].v, b1f, a1, 0, 0, 0);
            }
            // tanh + C-layout -> row-major repack (16 rows x 32 cols)
#pragma unroll
            for (int r = 0; r < 4; ++r) {
                mypk[(quad * 4 + r) * 32 + 0  + l15] = f2b(tanhf(xwv[0][r] + a0[r]));
                mypk[(quad * 4 + r) * 32 + 16 + l15] = f2b(tanhf(xwv[1][r] + a1[r]));
            }
            lds_repack_fence();
            {
                const uint64_t* pr = (const uint64_t*)mypk;   // [16][8] u64
                uint64_t v0 = pr[prow * 8 + pcg * 2];
                uint64_t v1 = pr[prow * 8 + pcg * 2 + 1];
                uint64_t* hdst = hr64 + (size_t)(t & 7) * 8192 + (size_t)(b0 + prow) * 128
                                 + (jw >> 2) + pcg * 2;
                st_st(hdst, v0);
                st_st(hdst + 1, v1);
            }
            if (lane == 0)   // ONE increment per wave (round-5 fix)
                __hip_atomic_fetch_add(hc, 1, __ATOMIC_RELEASE, __HIP_MEMORY_SCOPE_AGENT);
        }
    } else {
        // ---------------- a-side ----------------
        const int idx = bid - 16;
        const int g   = idx >> 3;
        const int b0  = g * 16;
        const int jw  = (idx & 7) * 64 + wave * 16;
        int* hc = ctr + g * 64;
        int* ac = ctr + (4 + g) * 64;

        // stage private Wya (s=0) and Waa (s=1) B-frags
#pragma unroll
        for (int m = 0; m < 2; ++m)
#pragma unroll
            for (int kb = 0; kb < 16; ++kb) {
                const unsigned short* wb = m ? Waa_b : Wya_b;
                const unsigned short* src = wb + (size_t)(jw + l15) * H_ + kb * 32 + quad * 8;
                *(uint4*)&wlds[(((wave * 2 + m) * 16 + kb) * 64 + lane) * 8] = *(const uint4*)src;
            }
        lds_repack_fence();
        const float bias_a = b_ya[jw + l15] + b_aa[jw + l15];

        unsigned short* mypk = &pk[wave][0];
        const int prow = lane >> 2, pcg = lane & 3;

        for (int t = 1; t <= S_; ++t) {
            // h_t first (h-chain leads; this poll is usually pre-satisfied)
            while (ctr_ld(hc) < 16 * t) {}
            poll_fence();
            const uint64_t* hsrc = hr64 + (size_t)(t & 7) * 8192 + (size_t)(b0 + l15) * 128 + quad * 2;
            union { uint64_t q[2]; bf16x8 v; } hf[16];
#pragma unroll
            for (int kb = 0; kb < 16; ++kb) {
                hf[kb].q[0] = st_ld(hsrc + kb * 8);
                hf[kb].q[1] = st_ld(hsrc + kb * 8 + 1);
            }
            f32x4 accy = {0.f, 0.f, 0.f, 0.f};
#pragma unroll
            for (int kb = 0; kb < 16; ++kb) {
                bf16x8 by = *(const bf16x8*)&wlds[(((wave * 2 + 0) * 16 + kb) * 64 + lane) * 8];
                accy = __builtin_amdgcn_mfma_f32_16x16x32_bf16(hf[kb].v, by, accy, 0, 0, 0);
            }
            // a_{t-1}
            while (ctr_ld(ac) < 32 * (t - 1)) {}
            poll_fence();
            const uint64_t* asrc = ar64 + (size_t)((t - 1) & 1) * 8192 + (size_t)(b0 + l15) * 128 + quad * 2;
            union { uint64_t q[2]; bf16x8 v; } af[16];
#pragma unroll
            for (int kb = 0; kb < 16; ++kb) {
                af[kb].q[0] = st_ld(asrc + kb * 8);
                af[kb].q[1] = st_ld(asrc + kb * 8 + 1);
            }
            f32x4 acca = {0.f, 0.f, 0.f, 0.f};
#pragma unroll
            for (int kb = 0; kb < 16; ++kb) {
                bf16x8 ba = *(const bf16x8*)&wlds[(((wave * 2 + 1) * 16 + kb) * 64 + lane) * 8];
                acca = __builtin_amdgcn_mfma_f32_16x16x32_bf16(af[kb].v, ba, acca, 0, 0, 0);
            }
            float av[4];
#pragma unroll
            for (int r = 0; r < 4; ++r)
                av[r] = tanhf(accy[r] + acca[r] + bias_a);

            if (t < S_) {
#pragma unroll
                for (int r = 0; r < 4; ++r)
                    mypk[(quad * 4 + r) * 16 + l15] = f2b(av[r]);
                lds_repack_fence();
                uint64_t v = ((const uint64_t*)mypk)[prow * 4 + pcg];
                uint64_t* adst = ar64 + (size_t)(t & 1) * 8192 + (size_t)(b0 + prow) * 128
                                 + (jw >> 2) + pcg;
                st_st(adst, v);
            } else {
#pragma unroll
                for (int r = 0; r < 4; ++r)
                    out[(size_t)(b0 + quad * 4 + r) * E_ + jw + l15] = av[r];
            }
            if (lane == 0)   // ONE increment per wave (round-5 fix)
                __hip_atomic_fetch_add(ac, 1, __ATOMIC_RELEASE, __HIP_MEMORY_SCOPE_AGENT);
        }
    }
}

extern "C" void kernel_launch(void* const* d_in, const int* in_sizes, int n_in,
                              void* d_out, int out_size, void* d_ws, size_t ws_size,
                              hipStream_t stream) {
    const float* x    = (const float*)d_in[0];
    const float* W_ih = (const float*)d_in[1];
    const float* W_hh = (const float*)d_in[2];
    const float* b_ih = (const float*)d_in[3];
    const float* b_hh = (const float*)d_in[4];
    const float* W_ya = (const float*)d_in[5];
    const float* b_ya = (const float*)d_in[6];
    const float* W_aa = (const float*)d_in[7];
    const float* b_aa = (const float*)d_in[8];
    float* out = (float*)d_out;

    char* ws = (char*)d_ws;
    const size_t MB = 1024 * 1024, KB = 1024;
    float*          xw    = (float*)(ws);                              // 64 MB
    unsigned short* Whh_b = (unsigned short*)(ws + 64 * MB);           // 512 KB
    unsigned short* Wya_b = (unsigned short*)(ws + 64 * MB + 512 * KB);
    unsigned short* Waa_b = (unsigned short*)(ws + 65 * MB);           // 512 KB
    unsigned short* hring = (unsigned short*)(ws + 65 * MB + 512 * KB);// 512 KB (8 slots)
    unsigned short* aring = (unsigned short*)(ws + 66 * MB);           // 128 KB (2 slots)
    int*            ctr   = (int*)(ws + 66 * MB + 128 * KB);           // 2 KB

    conv_bf16<<<(H_ * H_) / 256, 256, 0, stream>>>(W_hh, W_ya, W_aa, Whh_b, Wya_b, Waa_b);

    // zero hring (512 KB) + aring (128 KB) contiguous = 163840 u32, then ctrs
    init_state<<<640, 256, 0, stream>>>((uint32_t*)hring, 163840);
    init_state<<<2,   256, 0, stream>>>((uint32_t*)ctr, 512);

    dim3 gg(H_ / 64, (S_ * B_) / 64);
    xw_gemm<<<gg, 256, 0, stream>>>(x, W_ih, b_ih, b_hh, xw);

    scan_mfma<<<48, 256, 0, stream>>>(xw, Whh_b, Wya_b, Waa_b, b_ya, b_aa,
                                      hring, aring, ctr, out);
}